// Round 18
// baseline (525.705 us; speedup 1.0000x reference)
//
#include <hip/hip_runtime.h>
#include <hip/hip_bf16.h>

#define N_NODES 50000
#define N_EDGES 800000
#define FIN 256
#define EMB 128
#define NGRAPH 256
#define TOT_E (N_EDGES + N_NODES)
#define NP 98              // partitions of 512 dst nodes (d >> 9)
#define RBLK 196           // radix blocks; 196 * 4096 edges >= 800000

typedef __bf16 bf16;
typedef __attribute__((ext_vector_type(8))) __bf16 bf16x8;
typedef __attribute__((ext_vector_type(4))) __bf16 bf16x4;
typedef __attribute__((ext_vector_type(4))) float f32x4;
typedef __attribute__((ext_vector_type(4))) int i32x4;

// ---------------- setup: hist_part + W transposes + pool-accumulator zero ---------
// One launch, role-split by blockIdx. r18 FIX: transpose needs 49152 threads
// (FIN*EMB + EMB*EMB); r17 allotted 96 blocks (24576) -> WT1 cols 96..127 and all
// of WT2 never written (silent-stale pages made it absmax 0.031, not catastrophic).
__global__ __launch_bounds__(256)
void setup_kernel(const int* __restrict__ e_dst, int* __restrict__ mat,
                  const float* __restrict__ W1, bf16* __restrict__ WT1,
                  const float* __restrict__ W2, bf16* __restrict__ WT2,
                  float* __restrict__ pmean, unsigned* __restrict__ pmaxu) {
    __shared__ int lh[NP];
    int b = blockIdx.x, t = threadIdx.x;
    if (b < RBLK) {
        for (int k = t; k < NP; k += 256) lh[k] = 0;
        __syncthreads();
        const int NQ = N_EDGES / 4;
        int base = b * 1024;
#pragma unroll
        for (int j = 0; j < 4; ++j) {
            int i = base + j * 256 + t;
            if (i < NQ) {
                i32x4 d4 = *(const i32x4*)(e_dst + 4 * i);
#pragma unroll
                for (int k = 0; k < 4; ++k) atomicAdd(&lh[d4[k] >> 9], 1);
            }
        }
        __syncthreads();
        for (int k = t; k < NP; k += 256) mat[k * RBLK + b] = lh[k];
    } else if (b < RBLK + 192) {
        int u = (b - RBLK) * 256 + t;              // 0..49151
        if (u < FIN * EMB) {                       // WT1[c][r] = W1[r][c]
            int c = u / FIN, r = u - c * FIN;
            WT1[u] = (bf16)W1[r * EMB + c];
        } else {
            int v = u - FIN * EMB;                 // WT2, v in [0, EMB*EMB)
            int c = v / EMB, r = v - c * EMB;
            WT2[v] = (bf16)W2[r * EMB + c];
        }
    } else {
        int u = (b - RBLK - 192) * 256 + t;        // 16 blocks x 256 = 4096
        for (int i = u; i < NGRAPH * EMB; i += 4096) {
            pmean[i] = 0.f;
            pmaxu[i] = 0u;                          // < transform of any real value
        }
    }
}

// Coalesced per-row exclusive scan of mat[NP][RBLK]; rowsum[p] = row total.
__global__ __launch_bounds__(256)
void rowscan_kernel(int* __restrict__ mat, int* __restrict__ rowsum) {
    __shared__ int lds[256];
    int p = blockIdx.x, t = threadIdx.x;
    int v = (t < RBLK) ? mat[p * RBLK + t] : 0;
    lds[t] = v;
    __syncthreads();
    for (int d = 1; d < 256; d <<= 1) {
        int u = (t >= d) ? lds[t - d] : 0;
        __syncthreads();
        lds[t] += u;
        __syncthreads();
    }
    if (t < RBLK) mat[p * RBLK + t] = lds[t] - v;
    if (t == 255) rowsum[p] = lds[255];
}

// Radix place: per-(block,partition) private sub-ranges (single-writer lines).
__global__ __launch_bounds__(256)
void radix_scatter_kernel(const int* __restrict__ e_src, const int* __restrict__ e_dst,
                          const int* __restrict__ mat, const int* __restrict__ rowsum,
                          unsigned* __restrict__ pairs) {
    __shared__ int ps[128], cur[NP];
    int t = threadIdx.x;
    int rv = 0;
    if (t < 128) { rv = (t < NP) ? rowsum[t] : 0; ps[t] = rv; }
    __syncthreads();
    for (int d = 1; d < 128; d <<= 1) {
        int u = (t < 128 && t >= d) ? ps[t - d] : 0;
        __syncthreads();
        if (t < 128) ps[t] += u;
        __syncthreads();
    }
    if (t < NP) cur[t] = (ps[t] - rv) + mat[t * RBLK + blockIdx.x];
    __syncthreads();
    const int NQ = N_EDGES / 4;
    int base = blockIdx.x * 1024;
#pragma unroll
    for (int j = 0; j < 4; ++j) {
        int i = base + j * 256 + t;
        if (i < NQ) {
            i32x4 d4 = *(const i32x4*)(e_dst + 4 * i);
            i32x4 s4 = *(const i32x4*)(e_src + 4 * i);
#pragma unroll
            for (int k = 0; k < 4; ++k) {
                int d = d4[k];
                int pos = atomicAdd(&cur[d >> 9], 1);
                pairs[pos] = ((unsigned)d << 16) | (unsigned)s4[k];   // d,s < 2^16
            }
        }
    }
}

// One block per 512-node partition: LDS hist of own pairs segment -> LDS scan ->
// offsets (+self-loop) -> place. All writes in private contiguous region.
__global__ __launch_bounds__(1024)
void part_build_kernel(const int* __restrict__ rowsum, const unsigned* __restrict__ pairs,
                       int* __restrict__ offsets, int* __restrict__ sorted) {
    int p = blockIdx.x, t = threadIdx.x;
    __shared__ int ps[128];
    __shared__ int sp0, sp1;
    if (t < 128) {
        int rv = (t < NP) ? rowsum[t] : 0;
        ps[t] = rv;
    }
    __syncthreads();
    for (int d = 1; d < 128; d <<= 1) {
        int u = (t < 128 && t >= d) ? ps[t - d] : 0;
        __syncthreads();
        if (t < 128) ps[t] += u;
        __syncthreads();
    }
    if (t == 0) {
        int excl = ps[p] - rowsum[p];
        sp0 = excl;
        sp1 = excl + rowsum[p];
    }
    __syncthreads();
    int p0 = sp0, p1 = sp1;
    int nbase = p * 512;
    int valid = N_NODES - nbase;
    valid = valid > 512 ? 512 : valid;           // 512, except 336 for p=97
    __shared__ int cnt[512], sc[512];
    if (t < 512) cnt[t] = (t < valid) ? 1 : 0;   // self-loop
    __syncthreads();
    for (int i = p0 + t; i < p1; i += 1024)
        atomicAdd(&cnt[(pairs[i] >> 16) & 511], 1);
    __syncthreads();
    int v = (t < 512) ? cnt[t] : 0;
    if (t < 512) sc[t] = v;
    __syncthreads();
    for (int d = 1; d < 512; d <<= 1) {          // Hillis-Steele inclusive
        int u = (t < 512 && t >= d) ? sc[t - d] : 0;
        __syncthreads();
        if (t < 512) sc[t] += u;
        __syncthreads();
    }
    int base = p0 + nbase;                       // edges-before + selfloops-before
    if (t < valid) {
        int off = base + (sc[t] - v);            // exclusive
        offsets[nbase + t] = off;
        sorted[off] = nbase + t;                 // self-loop at slot 0
        cnt[t] = off + 1;                        // global cursor
    }
    if (p == 0 && t == 0) offsets[N_NODES] = TOT_E;
    __syncthreads();
    for (int i = p0 + t; i < p1; i += 1024) {
        unsigned pr = pairs[i];
        int pos = atomicAdd(&cnt[(pr >> 16) & 511], 1);
        sorted[pos] = (int)(pr & 0xFFFFu);
    }
}

// ---------------- GEMM + fused scores (r15 structure: LDS, BK=64, swizzle, 32-row)
template<int K, typename AT>
__global__ __launch_bounds__(256)
void gemm_kernel(const AT* __restrict__ A, const bf16* __restrict__ WT,
                 bf16* __restrict__ C, int M,
                 const float* __restrict__ a_src, const float* __restrict__ a_dst,
                 float* __restrict__ s_src, float* __restrict__ s_dst) {
    __shared__ __align__(16) bf16 As[32][64];    //  4 KB
    __shared__ __align__(16) bf16 Bs[128][64];   // 16 KB
    __shared__ float sbuf[2][32];
    int tid = threadIdx.x;
    int wave = tid >> 6, lane = tid & 63;
    int rowHalf = wave & 1, colHalf = wave >> 1;
    int m0 = blockIdx.x * 32;

    f32x4 acc[4];
#pragma unroll
    for (int i = 0; i < 4; ++i) acc[i] = (f32x4){0.f, 0.f, 0.f, 0.f};

    for (int k0 = 0; k0 < K; k0 += 64) {
        if constexpr (sizeof(AT) == 4) {
#pragma unroll
            for (int it = 0; it < 2; ++it) {               // 32 rows x 16 seg4
                int task = tid + it * 256;
                int row = task >> 4, seg4 = task & 15;
                int gr = m0 + row;
                float4 f = make_float4(0.f, 0.f, 0.f, 0.f);
                if (gr < M) f = *(const float4*)((const float*)A + (size_t)gr * K + k0 + seg4 * 4);
                bf16x4 b4 = (bf16x4){(bf16)f.x, (bf16)f.y, (bf16)f.z, (bf16)f.w};
                int slot = seg4 >> 1, half8 = seg4 & 1;
                int ss = slot ^ (row & 7);
                *(bf16x4*)(&As[row][ss * 8 + half8 * 4]) = b4;
            }
        } else {
            int row = tid >> 3, slot = tid & 7;            // 32 rows x 8 slots
            int gr = m0 + row;
            uint4 v = make_uint4(0u, 0u, 0u, 0u);
            if (gr < M) v = *(const uint4*)((const bf16*)A + (size_t)gr * K + k0 + slot * 8);
            int ss = slot ^ (row & 7);
            *(uint4*)(&As[row][ss * 8]) = v;
        }
#pragma unroll
        for (int it = 0; it < 4; ++it) {                   // 128 cols x 8 slots
            int task = tid + it * 256;
            int col = task >> 3, slot = task & 7;
            uint4 v = *(const uint4*)(WT + (size_t)col * K + k0 + slot * 8);
            int ss = slot ^ (col & 7);
            *(uint4*)(&Bs[col][ss * 8]) = v;
        }
        __syncthreads();
        int tr = rowHalf * 16 + (lane & 15);
        int kseg = lane >> 4;                              // 0..3
        bf16x8 af0 = *(const bf16x8*)(&As[tr][((kseg) ^ (tr & 7)) * 8]);
        bf16x8 af1 = *(const bf16x8*)(&As[tr][((4 + kseg) ^ (tr & 7)) * 8]);
#pragma unroll
        for (int n = 0; n < 4; ++n) {
            int c = colHalf * 64 + n * 16 + (lane & 15);
            bf16x8 b0 = *(const bf16x8*)(&Bs[c][((kseg) ^ (c & 7)) * 8]);
            bf16x8 b1 = *(const bf16x8*)(&Bs[c][((4 + kseg) ^ (c & 7)) * 8]);
            acc[n] = __builtin_amdgcn_mfma_f32_16x16x32_bf16(af0, b0, acc[n], 0, 0, 0);
            acc[n] = __builtin_amdgcn_mfma_f32_16x16x32_bf16(af1, b1, acc[n], 0, 0, 0);
        }
        __syncthreads();
    }
    int rbase = m0 + rowHalf * 16 + ((lane >> 4) << 2);
    int cb = lane & 15;
#pragma unroll
    for (int n = 0; n < 4; ++n) {
        int col = colHalf * 64 + n * 16 + cb;
#pragma unroll
        for (int rr = 0; rr < 4; ++rr) {
            int row = rbase + rr;
            if (row < M) C[(size_t)row * 128 + col] = (bf16)acc[n][rr];
        }
    }
    // fused scores epilogue (cross col-half combine via LDS)
    if (tid < 64) sbuf[tid >> 5][tid & 31] = 0.f;
    __syncthreads();
    float a_s[4], a_d[4];
#pragma unroll
    for (int n = 0; n < 4; ++n) {
        a_s[n] = a_src[colHalf * 64 + n * 16 + cb];
        a_d[n] = a_dst[colHalf * 64 + n * 16 + cb];
    }
#pragma unroll
    for (int rr = 0; rr < 4; ++rr) {
        float ps = 0.f, pd = 0.f;
#pragma unroll
        for (int n = 0; n < 4; ++n) {
            ps += acc[n][rr] * a_s[n];
            pd += acc[n][rr] * a_d[n];
        }
#pragma unroll
        for (int mk = 8; mk >= 1; mk >>= 1) {
            ps += __shfl_xor(ps, mk);
            pd += __shfl_xor(pd, mk);
        }
        if (cb == 0) {
            int tr16 = rowHalf * 16 + (lane >> 4) * 4 + rr;
            atomicAdd(&sbuf[0][tr16], ps);
            atomicAdd(&sbuf[1][tr16], pd);
        }
    }
    __syncthreads();
    if (tid < 32 && m0 + tid < M) {
        s_src[m0 + tid] = sbuf[0][tid];
        s_dst[m0 + tid] = sbuf[1][tid];
    }
}

// ---------------- per-node softmax-aggregate; POOL variant fuses graph pooling ----
template<bool POOL>
__global__ __launch_bounds__(256)
void agg_kernel(const int* __restrict__ offsets, const int* __restrict__ sorted_src,
                const float* __restrict__ s_src, const float* __restrict__ s_dst,
                const bf16* __restrict__ h, const float* __restrict__ bias,
                bf16* __restrict__ out, const int* __restrict__ batch,
                float* __restrict__ pmean, unsigned* __restrict__ pmaxu) {
    int tid = threadIdx.x;
    int wave = tid >> 6, lane = tid & 63;
    int gl = lane & 15;
    int gbase = lane & 48;
    int d = blockIdx.x * 16 + wave * 4 + (lane >> 4);
    if (d >= N_NODES) return;
    int r0 = offsets[d];
    int deg = offsets[d + 1] - r0;
    float sd = s_dst[d];

    int sv0 = 0, sv1 = 0;
    float ev0 = -INFINITY, ev1 = -INFINITY;
    if (gl < deg) {
        sv0 = sorted_src[r0 + gl];
        float e = s_src[sv0] + sd;
        ev0 = (e > 0.f) ? e : 0.2f * e;
    }
    if (16 + gl < deg) {
        sv1 = sorted_src[r0 + 16 + gl];
        float e = s_src[sv1] + sd;
        ev1 = (e > 0.f) ? e : 0.2f * e;
    }
    float m = fmaxf(ev0, ev1);
    for (int i = 32 + gl; i < deg; i += 16) {
        int s = sorted_src[r0 + i];
        float e = s_src[s] + sd;
        e = (e > 0.f) ? e : 0.2f * e;
        m = fmaxf(m, e);
    }
#pragma unroll
    for (int mk = 8; mk >= 1; mk >>= 1) m = fmaxf(m, __shfl_xor(m, mk));

    float pv0 = (gl < deg) ? __expf(ev0 - m) : 0.f;
    float pv1 = (16 + gl < deg) ? __expf(ev1 - m) : 0.f;
    float den = pv0 + pv1;
    for (int i = 32 + gl; i < deg; i += 16) {
        int s = sorted_src[r0 + i];
        float e = s_src[s] + sd;
        e = (e > 0.f) ? e : 0.2f * e;
        den += __expf(e - m);
    }
#pragma unroll
    for (int mk = 8; mk >= 1; mk >>= 1) den += __shfl_xor(den, mk);

    float acc[8];
#pragma unroll
    for (int k = 0; k < 8; ++k) acc[k] = 0.f;

    int jm = (deg < 32) ? deg : 32;
#pragma unroll 8
    for (int j = 0; j < jm; ++j) {
        int src_lane = gbase + (j & 15);
        int s = __shfl((j < 16) ? sv0 : sv1, src_lane);
        float p = __shfl((j < 16) ? pv0 : pv1, src_lane);
        bf16x8 hv = *(const bf16x8*)(h + (size_t)s * 128 + gl * 8);
#pragma unroll
        for (int k = 0; k < 8; ++k) acc[k] += p * (float)hv[k];
    }
    for (int i = 32; i < deg; ++i) {
        int s = sorted_src[r0 + i];
        float e = s_src[s] + sd;
        e = (e > 0.f) ? e : 0.2f * e;
        float p = __expf(e - m);
        bf16x8 hv = *(const bf16x8*)(h + (size_t)s * 128 + gl * 8);
#pragma unroll
        for (int k = 0; k < 8; ++k) acc[k] += p * (float)hv[k];
    }

    float inv = 1.f / den;
    float4 bv0 = *(const float4*)(bias + gl * 8);
    float4 bv1 = *(const float4*)(bias + gl * 8 + 4);
    float o[8] = {acc[0] * inv + bv0.x, acc[1] * inv + bv0.y,
                  acc[2] * inv + bv0.z, acc[3] * inv + bv0.w,
                  acc[4] * inv + bv1.x, acc[5] * inv + bv1.y,
                  acc[6] * inv + bv1.z, acc[7] * inv + bv1.w};
    if constexpr (POOL) {
        int g = batch[d];
#pragma unroll
        for (int k = 0; k < 8; ++k) {
            atomicAdd(&pmean[g * 128 + gl * 8 + k], o[k]);
            unsigned bts = __float_as_uint(o[k]);
            unsigned mu = (bts & 0x80000000u) ? ~bts : (bts | 0x80000000u);
            atomicMax(&pmaxu[g * 128 + gl * 8 + k], mu);
        }
    } else {
        bf16x8 ov;
#pragma unroll
        for (int k = 0; k < 8; ++k) ov[k] = (bf16)o[k];
        *(bf16x8*)(out + (size_t)d * 128 + gl * 8) = ov;
    }
}

// ---------------- head: counts via binary search; reads fused-pool accumulators ---
__global__ __launch_bounds__(128)
void head_kernel(const float* __restrict__ pmean, const unsigned* __restrict__ pmaxu,
                 const int* __restrict__ batch_idx,
                 const float* __restrict__ gfeat, const float* __restrict__ Wg,
                 const float* __restrict__ bg, const float* __restrict__ Wo,
                 const float* __restrict__ bo, float* __restrict__ out) {
    int g = blockIdx.x;
    int j = threadIdx.x;
    int lo = 0, hi = N_NODES;
    while (lo < hi) { int mid = (lo + hi) >> 1; if (batch_idx[mid] < g) lo = mid + 1; else hi = mid; }
    int start = lo;
    hi = N_NODES;
    while (lo < hi) { int mid = (lo + hi) >> 1; if (batch_idx[mid] < g + 1) lo = mid + 1; else hi = mid; }
    int cnt = lo - start;

    float mj = pmean[g * 128 + j] / fmaxf((float)cnt, 1.f);
    float xj = 0.f;
    if (cnt > 0) {
        unsigned mu = pmaxu[g * 128 + j];
        unsigned bts = (mu & 0x80000000u) ? (mu ^ 0x80000000u) : ~mu;
        xj = __uint_as_float(bts);
    }
    float gft = bg[j];
#pragma unroll
    for (int k = 0; k < 32; ++k)
        gft += gfeat[g * 32 + k] * Wg[k * 128 + j];
    float p0 = mj * Wo[j * 2 + 0] + xj * Wo[(128 + j) * 2 + 0] + gft * Wo[(256 + j) * 2 + 0];
    float p1 = mj * Wo[j * 2 + 1] + xj * Wo[(128 + j) * 2 + 1] + gft * Wo[(256 + j) * 2 + 1];
#pragma unroll
    for (int m = 32; m >= 1; m >>= 1) { p0 += __shfl_xor(p0, m); p1 += __shfl_xor(p1, m); }
    __shared__ float l0s[2], l1s[2];
    int wv = j >> 6;
    if ((j & 63) == 0) { l0s[wv] = p0; l1s[wv] = p1; }
    __syncthreads();
    if (j == 0) {
        float l0 = l0s[0] + l0s[1] + bo[0];
        float l1 = l1s[0] + l1s[1] + bo[1];
        float mm = fmaxf(l0, l1);
        float lse = mm + logf(__expf(l0 - mm) + __expf(l1 - mm));
        out[g * 2 + 0] = l0 - lse;
        out[g * 2 + 1] = l1 - lse;
    }
}

extern "C" void kernel_launch(void* const* d_in, const int* in_sizes, int n_in,
                              void* d_out, int out_size, void* d_ws, size_t ws_size,
                              hipStream_t stream) {
    const float* x     = (const float*)d_in[0];
    const int*   edges = (const int*)d_in[1];
    const int*   batch = (const int*)d_in[2];
    const float* gfeat = (const float*)d_in[3];
    const float* W1    = (const float*)d_in[4];
    const float* a1s   = (const float*)d_in[5];
    const float* a1d   = (const float*)d_in[6];
    const float* b1    = (const float*)d_in[7];
    const float* W2    = (const float*)d_in[8];
    const float* a2s   = (const float*)d_in[9];
    const float* a2d   = (const float*)d_in[10];
    const float* b2    = (const float*)d_in[11];
    const float* Wg    = (const float*)d_in[12];
    const float* bg    = (const float*)d_in[13];
    const float* Wo    = (const float*)d_in[14];
    const float* bo    = (const float*)d_in[15];

    char* ws = (char*)d_ws;
    bf16*     WT1       = (bf16*)(ws + 0);          //  65536 B
    bf16*     WT2       = (bf16*)(ws + 65536);      //  32768 B
    float*    s_src     = (float*)(ws + 98304);     // 200704 B
    float*    s_dst     = (float*)(ws + 299008);    // 200704 B
    int*      mat       = (int*)(ws + 700672);      // 76832 B
    int*      rowsum    = (int*)(ws + 777536);      // 392 B
    int*      offsets   = (int*)(ws + 778432);      // 200704 B (N+1 ints)
    int*      sorted    = (int*)(ws + 979136);      // 3400704 B
    bf16*     h         = (bf16*)(ws + 4502528);    // 12.8 MB
    bf16*     out1      = (bf16*)(ws + 17302528);   // 12.8 MB
    unsigned* pairs     = (unsigned*)(ws + 43002528); // 3.2 MB
    float*    pmean     = (float*)(ws + 55702528);  // 131072 B (raw sums)
    unsigned* pmaxu     = (unsigned*)(ws + 55833600); // 131072 B (transformed max)

    const int* e_src = edges;
    const int* e_dst = edges + N_EDGES;

    // --- setup: partition hist + W transposes + pool-accumulator zero (1 launch) ---
    setup_kernel<<<RBLK + 192 + 16, 256, 0, stream>>>(e_dst, mat, W1, WT1, W2, WT2,
                                                      pmean, pmaxu);
    rowscan_kernel<<<NP, 256, 0, stream>>>(mat, rowsum);
    radix_scatter_kernel<<<RBLK, 256, 0, stream>>>(e_src, e_dst, mat, rowsum, pairs);
    part_build_kernel<<<NP, 1024, 0, stream>>>(rowsum, pairs, offsets, sorted);

    int gemm_blocks = (N_NODES + 31) / 32;   // 1563
    int agg_blocks = (N_NODES + 15) / 16;

    // --- layer 1 (scores fused into gemm epilogue) ---
    gemm_kernel<FIN, float><<<gemm_blocks, 256, 0, stream>>>(x, WT1, h, N_NODES,
                                                             a1s, a1d, s_src, s_dst);
    agg_kernel<false><<<agg_blocks, 256, 0, stream>>>(offsets, sorted, s_src, s_dst,
                                                      h, b1, out1, batch, pmean, pmaxu);

    // --- layer 2 (pooling fused into agg via atomics) ---
    gemm_kernel<EMB, bf16><<<gemm_blocks, 256, 0, stream>>>(out1, WT2, h, N_NODES,
                                                            a2s, a2d, s_src, s_dst);
    agg_kernel<true><<<agg_blocks, 256, 0, stream>>>(offsets, sorted, s_src, s_dst,
                                                     h, b2, nullptr, batch, pmean, pmaxu);

    // --- head ---
    head_kernel<<<NGRAPH, 128, 0, stream>>>(pmean, pmaxu, batch, gfeat, Wg, bg, Wo, bo,
                                            (float*)d_out);
}

// Round 19
// 172.388 us; speedup vs baseline: 3.0495x; 3.0495x over previous
//
#include <hip/hip_runtime.h>
#include <hip/hip_bf16.h>

#define N_NODES 50000
#define N_EDGES 800000
#define FIN 256
#define EMB 128
#define NGRAPH 256
#define TOT_E (N_EDGES + N_NODES)
#define NP 98              // partitions of 512 dst nodes (d >> 9)
#define RBLK 196           // radix blocks; 196 * 4096 edges >= 800000

typedef __bf16 bf16;
typedef __attribute__((ext_vector_type(8))) __bf16 bf16x8;
typedef __attribute__((ext_vector_type(4))) __bf16 bf16x4;
typedef __attribute__((ext_vector_type(4))) float f32x4;
typedef __attribute__((ext_vector_type(4))) int i32x4;

// ---------------- setup: hist_part + both W transposes (one launch) ---------------
// r18 post-mortem: pool fusion via global atomics = 425us (12.8M RMW atomics onto
// 65k cross-XCD lines -> 400MB write amp). Reverted to r16's agg->out2->pool path;
// kept this launch consolidation (r17) with the corrected 192 transpose blocks.
__global__ __launch_bounds__(256)
void setup_kernel(const int* __restrict__ e_dst, int* __restrict__ mat,
                  const float* __restrict__ W1, bf16* __restrict__ WT1,
                  const float* __restrict__ W2, bf16* __restrict__ WT2) {
    __shared__ int lh[NP];
    int b = blockIdx.x, t = threadIdx.x;
    if (b < RBLK) {
        for (int k = t; k < NP; k += 256) lh[k] = 0;
        __syncthreads();
        const int NQ = N_EDGES / 4;
        int base = b * 1024;
#pragma unroll
        for (int j = 0; j < 4; ++j) {
            int i = base + j * 256 + t;
            if (i < NQ) {
                i32x4 d4 = *(const i32x4*)(e_dst + 4 * i);
#pragma unroll
                for (int k = 0; k < 4; ++k) atomicAdd(&lh[d4[k] >> 9], 1);
            }
        }
        __syncthreads();
        for (int k = t; k < NP; k += 256) mat[k * RBLK + b] = lh[k];
    } else {
        int u = (b - RBLK) * 256 + t;              // 0..49151 (192 blocks)
        if (u < FIN * EMB) {                       // WT1[c][r] = W1[r][c]
            int c = u / FIN, r = u - c * FIN;
            WT1[u] = (bf16)W1[r * EMB + c];
        } else {
            int v = u - FIN * EMB;                 // WT2, v in [0, EMB*EMB)
            int c = v / EMB, r = v - c * EMB;
            WT2[v] = (bf16)W2[r * EMB + c];
        }
    }
}

// Coalesced per-row exclusive scan of mat[NP][RBLK]; rowsum[p] = row total.
__global__ __launch_bounds__(256)
void rowscan_kernel(int* __restrict__ mat, int* __restrict__ rowsum) {
    __shared__ int lds[256];
    int p = blockIdx.x, t = threadIdx.x;
    int v = (t < RBLK) ? mat[p * RBLK + t] : 0;
    lds[t] = v;
    __syncthreads();
    for (int d = 1; d < 256; d <<= 1) {
        int u = (t >= d) ? lds[t - d] : 0;
        __syncthreads();
        lds[t] += u;
        __syncthreads();
    }
    if (t < RBLK) mat[p * RBLK + t] = lds[t] - v;
    if (t == 255) rowsum[p] = lds[255];
}

// Radix place: per-(block,partition) private sub-ranges (single-writer lines).
__global__ __launch_bounds__(256)
void radix_scatter_kernel(const int* __restrict__ e_src, const int* __restrict__ e_dst,
                          const int* __restrict__ mat, const int* __restrict__ rowsum,
                          unsigned* __restrict__ pairs) {
    __shared__ int ps[128], cur[NP];
    int t = threadIdx.x;
    int rv = 0;
    if (t < 128) { rv = (t < NP) ? rowsum[t] : 0; ps[t] = rv; }
    __syncthreads();
    for (int d = 1; d < 128; d <<= 1) {
        int u = (t < 128 && t >= d) ? ps[t - d] : 0;
        __syncthreads();
        if (t < 128) ps[t] += u;
        __syncthreads();
    }
    if (t < NP) cur[t] = (ps[t] - rv) + mat[t * RBLK + blockIdx.x];
    __syncthreads();
    const int NQ = N_EDGES / 4;
    int base = blockIdx.x * 1024;
#pragma unroll
    for (int j = 0; j < 4; ++j) {
        int i = base + j * 256 + t;
        if (i < NQ) {
            i32x4 d4 = *(const i32x4*)(e_dst + 4 * i);
            i32x4 s4 = *(const i32x4*)(e_src + 4 * i);
#pragma unroll
            for (int k = 0; k < 4; ++k) {
                int d = d4[k];
                int pos = atomicAdd(&cur[d >> 9], 1);
                pairs[pos] = ((unsigned)d << 16) | (unsigned)s4[k];   // d,s < 2^16
            }
        }
    }
}

// One block per 512-node partition: LDS hist of own pairs segment -> LDS scan ->
// offsets (+self-loop) -> place. All writes in private contiguous region.
__global__ __launch_bounds__(1024)
void part_build_kernel(const int* __restrict__ rowsum, const unsigned* __restrict__ pairs,
                       int* __restrict__ offsets, int* __restrict__ sorted) {
    int p = blockIdx.x, t = threadIdx.x;
    __shared__ int ps[128];
    __shared__ int sp0, sp1;
    if (t < 128) {
        int rv = (t < NP) ? rowsum[t] : 0;
        ps[t] = rv;
    }
    __syncthreads();
    for (int d = 1; d < 128; d <<= 1) {
        int u = (t < 128 && t >= d) ? ps[t - d] : 0;
        __syncthreads();
        if (t < 128) ps[t] += u;
        __syncthreads();
    }
    if (t == 0) {
        int excl = ps[p] - rowsum[p];
        sp0 = excl;
        sp1 = excl + rowsum[p];
    }
    __syncthreads();
    int p0 = sp0, p1 = sp1;
    int nbase = p * 512;
    int valid = N_NODES - nbase;
    valid = valid > 512 ? 512 : valid;           // 512, except 336 for p=97
    __shared__ int cnt[512], sc[512];
    if (t < 512) cnt[t] = (t < valid) ? 1 : 0;   // self-loop
    __syncthreads();
    for (int i = p0 + t; i < p1; i += 1024)
        atomicAdd(&cnt[(pairs[i] >> 16) & 511], 1);
    __syncthreads();
    int v = (t < 512) ? cnt[t] : 0;
    if (t < 512) sc[t] = v;
    __syncthreads();
    for (int d = 1; d < 512; d <<= 1) {          // Hillis-Steele inclusive
        int u = (t < 512 && t >= d) ? sc[t - d] : 0;
        __syncthreads();
        if (t < 512) sc[t] += u;
        __syncthreads();
    }
    int base = p0 + nbase;                       // edges-before + selfloops-before
    if (t < valid) {
        int off = base + (sc[t] - v);            // exclusive
        offsets[nbase + t] = off;
        sorted[off] = nbase + t;                 // self-loop at slot 0
        cnt[t] = off + 1;                        // global cursor
    }
    if (p == 0 && t == 0) offsets[N_NODES] = TOT_E;
    __syncthreads();
    for (int i = p0 + t; i < p1; i += 1024) {
        unsigned pr = pairs[i];
        int pos = atomicAdd(&cnt[(pr >> 16) & 511], 1);
        sorted[pos] = (int)(pr & 0xFFFFu);
    }
}

// ---------------- GEMM + fused scores (r15 structure: LDS, BK=64, swizzle, 32-row)
template<int K, typename AT>
__global__ __launch_bounds__(256)
void gemm_kernel(const AT* __restrict__ A, const bf16* __restrict__ WT,
                 bf16* __restrict__ C, int M,
                 const float* __restrict__ a_src, const float* __restrict__ a_dst,
                 float* __restrict__ s_src, float* __restrict__ s_dst) {
    __shared__ __align__(16) bf16 As[32][64];    //  4 KB
    __shared__ __align__(16) bf16 Bs[128][64];   // 16 KB
    __shared__ float sbuf[2][32];
    int tid = threadIdx.x;
    int wave = tid >> 6, lane = tid & 63;
    int rowHalf = wave & 1, colHalf = wave >> 1;
    int m0 = blockIdx.x * 32;

    f32x4 acc[4];
#pragma unroll
    for (int i = 0; i < 4; ++i) acc[i] = (f32x4){0.f, 0.f, 0.f, 0.f};

    for (int k0 = 0; k0 < K; k0 += 64) {
        if constexpr (sizeof(AT) == 4) {
#pragma unroll
            for (int it = 0; it < 2; ++it) {               // 32 rows x 16 seg4
                int task = tid + it * 256;
                int row = task >> 4, seg4 = task & 15;
                int gr = m0 + row;
                float4 f = make_float4(0.f, 0.f, 0.f, 0.f);
                if (gr < M) f = *(const float4*)((const float*)A + (size_t)gr * K + k0 + seg4 * 4);
                bf16x4 b4 = (bf16x4){(bf16)f.x, (bf16)f.y, (bf16)f.z, (bf16)f.w};
                int slot = seg4 >> 1, half8 = seg4 & 1;
                int ss = slot ^ (row & 7);
                *(bf16x4*)(&As[row][ss * 8 + half8 * 4]) = b4;
            }
        } else {
            int row = tid >> 3, slot = tid & 7;            // 32 rows x 8 slots
            int gr = m0 + row;
            uint4 v = make_uint4(0u, 0u, 0u, 0u);
            if (gr < M) v = *(const uint4*)((const bf16*)A + (size_t)gr * K + k0 + slot * 8);
            int ss = slot ^ (row & 7);
            *(uint4*)(&As[row][ss * 8]) = v;
        }
#pragma unroll
        for (int it = 0; it < 4; ++it) {                   // 128 cols x 8 slots
            int task = tid + it * 256;
            int col = task >> 3, slot = task & 7;
            uint4 v = *(const uint4*)(WT + (size_t)col * K + k0 + slot * 8);
            int ss = slot ^ (col & 7);
            *(uint4*)(&Bs[col][ss * 8]) = v;
        }
        __syncthreads();
        int tr = rowHalf * 16 + (lane & 15);
        int kseg = lane >> 4;                              // 0..3
        bf16x8 af0 = *(const bf16x8*)(&As[tr][((kseg) ^ (tr & 7)) * 8]);
        bf16x8 af1 = *(const bf16x8*)(&As[tr][((4 + kseg) ^ (tr & 7)) * 8]);
#pragma unroll
        for (int n = 0; n < 4; ++n) {
            int c = colHalf * 64 + n * 16 + (lane & 15);
            bf16x8 b0 = *(const bf16x8*)(&Bs[c][((kseg) ^ (c & 7)) * 8]);
            bf16x8 b1 = *(const bf16x8*)(&Bs[c][((4 + kseg) ^ (c & 7)) * 8]);
            acc[n] = __builtin_amdgcn_mfma_f32_16x16x32_bf16(af0, b0, acc[n], 0, 0, 0);
            acc[n] = __builtin_amdgcn_mfma_f32_16x16x32_bf16(af1, b1, acc[n], 0, 0, 0);
        }
        __syncthreads();
    }
    int rbase = m0 + rowHalf * 16 + ((lane >> 4) << 2);
    int cb = lane & 15;
#pragma unroll
    for (int n = 0; n < 4; ++n) {
        int col = colHalf * 64 + n * 16 + cb;
#pragma unroll
        for (int rr = 0; rr < 4; ++rr) {
            int row = rbase + rr;
            if (row < M) C[(size_t)row * 128 + col] = (bf16)acc[n][rr];
        }
    }
    // fused scores epilogue (cross col-half combine via LDS)
    if (tid < 64) sbuf[tid >> 5][tid & 31] = 0.f;
    __syncthreads();
    float a_s[4], a_d[4];
#pragma unroll
    for (int n = 0; n < 4; ++n) {
        a_s[n] = a_src[colHalf * 64 + n * 16 + cb];
        a_d[n] = a_dst[colHalf * 64 + n * 16 + cb];
    }
#pragma unroll
    for (int rr = 0; rr < 4; ++rr) {
        float ps = 0.f, pd = 0.f;
#pragma unroll
        for (int n = 0; n < 4; ++n) {
            ps += acc[n][rr] * a_s[n];
            pd += acc[n][rr] * a_d[n];
        }
#pragma unroll
        for (int mk = 8; mk >= 1; mk >>= 1) {
            ps += __shfl_xor(ps, mk);
            pd += __shfl_xor(pd, mk);
        }
        if (cb == 0) {
            int tr16 = rowHalf * 16 + (lane >> 4) * 4 + rr;
            atomicAdd(&sbuf[0][tr16], ps);
            atomicAdd(&sbuf[1][tr16], pd);
        }
    }
    __syncthreads();
    if (tid < 32 && m0 + tid < M) {
        s_src[m0 + tid] = sbuf[0][tid];
        s_dst[m0 + tid] = sbuf[1][tid];
    }
}

// ---------------- per-node softmax-aggregate (16-lane groups, 4 nodes/wave) -------
__global__ __launch_bounds__(256)
void agg_kernel(const int* __restrict__ offsets, const int* __restrict__ sorted_src,
                const float* __restrict__ s_src, const float* __restrict__ s_dst,
                const bf16* __restrict__ h, const float* __restrict__ bias,
                bf16* __restrict__ out) {
    int tid = threadIdx.x;
    int wave = tid >> 6, lane = tid & 63;
    int gl = lane & 15;
    int gbase = lane & 48;
    int d = blockIdx.x * 16 + wave * 4 + (lane >> 4);
    if (d >= N_NODES) return;
    int r0 = offsets[d];
    int deg = offsets[d + 1] - r0;
    float sd = s_dst[d];

    int sv0 = 0, sv1 = 0;
    float ev0 = -INFINITY, ev1 = -INFINITY;
    if (gl < deg) {
        sv0 = sorted_src[r0 + gl];
        float e = s_src[sv0] + sd;
        ev0 = (e > 0.f) ? e : 0.2f * e;
    }
    if (16 + gl < deg) {
        sv1 = sorted_src[r0 + 16 + gl];
        float e = s_src[sv1] + sd;
        ev1 = (e > 0.f) ? e : 0.2f * e;
    }
    float m = fmaxf(ev0, ev1);
    for (int i = 32 + gl; i < deg; i += 16) {
        int s = sorted_src[r0 + i];
        float e = s_src[s] + sd;
        e = (e > 0.f) ? e : 0.2f * e;
        m = fmaxf(m, e);
    }
#pragma unroll
    for (int mk = 8; mk >= 1; mk >>= 1) m = fmaxf(m, __shfl_xor(m, mk));

    float pv0 = (gl < deg) ? __expf(ev0 - m) : 0.f;
    float pv1 = (16 + gl < deg) ? __expf(ev1 - m) : 0.f;
    float den = pv0 + pv1;
    for (int i = 32 + gl; i < deg; i += 16) {
        int s = sorted_src[r0 + i];
        float e = s_src[s] + sd;
        e = (e > 0.f) ? e : 0.2f * e;
        den += __expf(e - m);
    }
#pragma unroll
    for (int mk = 8; mk >= 1; mk >>= 1) den += __shfl_xor(den, mk);

    float acc[8];
#pragma unroll
    for (int k = 0; k < 8; ++k) acc[k] = 0.f;

    int jm = (deg < 32) ? deg : 32;
#pragma unroll 8
    for (int j = 0; j < jm; ++j) {
        int src_lane = gbase + (j & 15);
        int s = __shfl((j < 16) ? sv0 : sv1, src_lane);
        float p = __shfl((j < 16) ? pv0 : pv1, src_lane);
        bf16x8 hv = *(const bf16x8*)(h + (size_t)s * 128 + gl * 8);
#pragma unroll
        for (int k = 0; k < 8; ++k) acc[k] += p * (float)hv[k];
    }
    for (int i = 32; i < deg; ++i) {
        int s = sorted_src[r0 + i];
        float e = s_src[s] + sd;
        e = (e > 0.f) ? e : 0.2f * e;
        float p = __expf(e - m);
        bf16x8 hv = *(const bf16x8*)(h + (size_t)s * 128 + gl * 8);
#pragma unroll
        for (int k = 0; k < 8; ++k) acc[k] += p * (float)hv[k];
    }

    float inv = 1.f / den;
    float4 bv0 = *(const float4*)(bias + gl * 8);
    float4 bv1 = *(const float4*)(bias + gl * 8 + 4);
    bf16x8 ov;
    ov[0] = (bf16)(acc[0] * inv + bv0.x);
    ov[1] = (bf16)(acc[1] * inv + bv0.y);
    ov[2] = (bf16)(acc[2] * inv + bv0.z);
    ov[3] = (bf16)(acc[3] * inv + bv0.w);
    ov[4] = (bf16)(acc[4] * inv + bv1.x);
    ov[5] = (bf16)(acc[5] * inv + bv1.y);
    ov[6] = (bf16)(acc[6] * inv + bv1.z);
    ov[7] = (bf16)(acc[7] * inv + bv1.w);
    *(bf16x8*)(out + (size_t)d * 128 + gl * 8) = ov;
}

// ---------------- per-graph mean/max pooling (bf16 input; batch_idx sorted) -------
__global__ __launch_bounds__(256)
void pool_kernel(const bf16* __restrict__ out2, const int* __restrict__ batch_idx,
                 float* __restrict__ mean, float* __restrict__ mx) {
    int g = blockIdx.x;
    int j = threadIdx.x & 127;
    int grp = threadIdx.x >> 7;
    int lo = 0, hi = N_NODES;
    while (lo < hi) { int mid = (lo + hi) >> 1; if (batch_idx[mid] < g) lo = mid + 1; else hi = mid; }
    int start = lo;
    hi = N_NODES;
    while (lo < hi) { int mid = (lo + hi) >> 1; if (batch_idx[mid] < g + 1) lo = mid + 1; else hi = mid; }
    int end = lo;

    float s = 0.f, mmax = -INFINITY;
    for (int r = start + grp; r < end; r += 2) {
        float v = (float)out2[(size_t)r * 128 + j];
        s += v;
        mmax = fmaxf(mmax, v);
    }
    __shared__ float ls[2][128], lm[2][128];
    ls[grp][j] = s; lm[grp][j] = mmax;
    __syncthreads();
    if (grp == 0) {
        int cnt = end - start;
        float sum = ls[0][j] + ls[1][j];
        float mv = fmaxf(lm[0][j], lm[1][j]);
        mean[g * 128 + j] = sum / fmaxf((float)cnt, 1.f);
        mx[g * 128 + j] = (cnt > 0) ? mv : 0.f;
    }
}

// ---------------- head ----------------
__global__ __launch_bounds__(128)
void head_kernel(const float* __restrict__ mean, const float* __restrict__ mx,
                 const float* __restrict__ gfeat, const float* __restrict__ Wg,
                 const float* __restrict__ bg, const float* __restrict__ Wo,
                 const float* __restrict__ bo, float* __restrict__ out) {
    int g = blockIdx.x;
    int j = threadIdx.x;
    float gft = bg[j];
#pragma unroll
    for (int k = 0; k < 32; ++k)
        gft += gfeat[g * 32 + k] * Wg[k * 128 + j];
    float mj = mean[g * 128 + j], xj = mx[g * 128 + j];
    float p0 = mj * Wo[j * 2 + 0] + xj * Wo[(128 + j) * 2 + 0] + gft * Wo[(256 + j) * 2 + 0];
    float p1 = mj * Wo[j * 2 + 1] + xj * Wo[(128 + j) * 2 + 1] + gft * Wo[(256 + j) * 2 + 1];
#pragma unroll
    for (int m = 32; m >= 1; m >>= 1) { p0 += __shfl_xor(p0, m); p1 += __shfl_xor(p1, m); }
    __shared__ float l0s[2], l1s[2];
    int wv = j >> 6;
    if ((j & 63) == 0) { l0s[wv] = p0; l1s[wv] = p1; }
    __syncthreads();
    if (j == 0) {
        float l0 = l0s[0] + l0s[1] + bo[0];
        float l1 = l1s[0] + l1s[1] + bo[1];
        float mm = fmaxf(l0, l1);
        float lse = mm + logf(__expf(l0 - mm) + __expf(l1 - mm));
        out[g * 2 + 0] = l0 - lse;
        out[g * 2 + 1] = l1 - lse;
    }
}

extern "C" void kernel_launch(void* const* d_in, const int* in_sizes, int n_in,
                              void* d_out, int out_size, void* d_ws, size_t ws_size,
                              hipStream_t stream) {
    const float* x     = (const float*)d_in[0];
    const int*   edges = (const int*)d_in[1];
    const int*   batch = (const int*)d_in[2];
    const float* gfeat = (const float*)d_in[3];
    const float* W1    = (const float*)d_in[4];
    const float* a1s   = (const float*)d_in[5];
    const float* a1d   = (const float*)d_in[6];
    const float* b1    = (const float*)d_in[7];
    const float* W2    = (const float*)d_in[8];
    const float* a2s   = (const float*)d_in[9];
    const float* a2d   = (const float*)d_in[10];
    const float* b2    = (const float*)d_in[11];
    const float* Wg    = (const float*)d_in[12];
    const float* bg    = (const float*)d_in[13];
    const float* Wo    = (const float*)d_in[14];
    const float* bo    = (const float*)d_in[15];

    char* ws = (char*)d_ws;
    bf16*     WT1       = (bf16*)(ws + 0);          //  65536 B
    bf16*     WT2       = (bf16*)(ws + 65536);      //  32768 B
    float*    s_src     = (float*)(ws + 98304);     // 200704 B
    float*    s_dst     = (float*)(ws + 299008);    // 200704 B
    int*      mat       = (int*)(ws + 700672);      // 76832 B
    int*      rowsum    = (int*)(ws + 777536);      // 392 B
    int*      offsets   = (int*)(ws + 778432);      // 200704 B (N+1 ints)
    int*      sorted    = (int*)(ws + 979136);      // 3400704 B
    bf16*     h         = (bf16*)(ws + 4502528);    // 12.8 MB
    bf16*     out1      = (bf16*)(ws + 17302528);   // 12.8 MB
    bf16*     out2      = (bf16*)(ws + 30102528);   // 12.8 MB
    unsigned* pairs     = (unsigned*)(ws + 43002528); // 3.2 MB
    float*    pmean     = (float*)(ws + 55702528);  // 131072 B
    float*    pmax      = (float*)(ws + 55833600);  // 131072 B

    const int* e_src = edges;
    const int* e_dst = edges + N_EDGES;

    // --- setup: partition hist + W transposes (1 launch) ---
    setup_kernel<<<RBLK + 192, 256, 0, stream>>>(e_dst, mat, W1, WT1, W2, WT2);
    rowscan_kernel<<<NP, 256, 0, stream>>>(mat, rowsum);
    radix_scatter_kernel<<<RBLK, 256, 0, stream>>>(e_src, e_dst, mat, rowsum, pairs);
    part_build_kernel<<<NP, 1024, 0, stream>>>(rowsum, pairs, offsets, sorted);

    int gemm_blocks = (N_NODES + 31) / 32;   // 1563
    int agg_blocks = (N_NODES + 15) / 16;

    // --- layer 1 (scores fused into gemm epilogue) ---
    gemm_kernel<FIN, float><<<gemm_blocks, 256, 0, stream>>>(x, WT1, h, N_NODES,
                                                             a1s, a1d, s_src, s_dst);
    agg_kernel<<<agg_blocks, 256, 0, stream>>>(offsets, sorted, s_src, s_dst, h, b1, out1);

    // --- layer 2 ---
    gemm_kernel<EMB, bf16><<<gemm_blocks, 256, 0, stream>>>(out1, WT2, h, N_NODES,
                                                            a2s, a2d, s_src, s_dst);
    agg_kernel<<<agg_blocks, 256, 0, stream>>>(offsets, sorted, s_src, s_dst, h, b2, out2);

    // --- pooling + head ---
    pool_kernel<<<NGRAPH, 256, 0, stream>>>(out2, batch, pmean, pmax);
    head_kernel<<<NGRAPH, 128, 0, stream>>>(pmean, pmax, gfeat, Wg, bg, Wo, bo, (float*)d_out);
}